// Round 3
// baseline (160.031 us; speedup 1.0000x reference)
//
#include <hip/hip_runtime.h>
#include <stdint.h>

// Binarized dense: C[r][u] = sum_k sign(x[r][k]) * sign(W[k][u]) + b[u]
//   sign(v) = +1 if v >= 0 else -1   -> bit(v) = (v < 0)
//   dot = F - 2 * popcount(xbits ^ wbits)
//
// Packed layout per row/col (F=4096 bits = 64 u64 words):
//   u64 word index w = c*4 + j,  c = 0..15 (256-float chunk), j = 0..3 (float4 comp)
//   bit i (0..63) of word (c,j) = bit(v[c*256 + i*4 + j])
//   In u32 view (as staged in LDS): u64 word w occupies u32 indices 2w, 2w+1.
// pack_w reproduces exactly this (c, j, lane) mapping.

#define BATCH  16384
#define INF    4096
#define UNITS  512
#define KW     128      // u32 words per row (4096/32)
#define KW64   64       // u64 words per row
#define ROWS   32       // x rows per block in fused kernel

// ---------------- pack W: [4096,512] f32 -> [512,64] u64 --------------------
__global__ __launch_bounds__(256) void pack_w_kernel(const float* __restrict__ W,
                                                     unsigned long long* __restrict__ Wp) {
    int t  = blockIdx.x * 256 + threadIdx.x;   // 0..32767
    int u  = t & 511;                          // column
    int cj = t >> 9;                           // 0..63 = c*4 + j
    int j  = cj & 3;
    int c  = cj >> 2;
    const float* base = W + (size_t)(c * 256 + j) * UNITS + u;
    unsigned long long m = 0;
    #pragma unroll 16
    for (int i = 0; i < 64; ++i) {
        // k = c*256 + 4*i + j ; addr = k*512 + u
        float v = base[(size_t)(4 * i) * UNITS];
        m |= (unsigned long long)(v < 0.f) << i;
    }
    Wp[(size_t)u * KW64 + cj] = m;
}

// ------------- fused: pack 32 x-rows to LDS bits, then bit-GEMM -------------
// Each block: 32 rows x all 512 units -> x read from HBM exactly once.
// sX: 32x132 u32 (16.9 KB), sW: 64x132 u32 (33.8 KB) -> ~51 KB, 2-3 blocks/CU.
__global__ __launch_bounds__(256) void fused_kernel(const float* __restrict__ x,
                                                    const uint32_t* __restrict__ Wp,
                                                    const float* __restrict__ bias,
                                                    float* __restrict__ C) {
    __shared__ uint32_t sX[ROWS][132];
    __shared__ uint32_t sW[64][132];
    const int t    = threadIdx.x;
    const int wid  = t >> 6;           // wave 0..3
    const int lane = t & 63;
    const int row0 = blockIdx.x * ROWS;

    // ---- Phase 1: pack. Wave w packs rows w*8 .. w*8+7 (16 chunks each). ----
    #pragma unroll 4
    for (int pp = 0; pp < 128; ++pp) {
        int r = wid * 8 + (pp >> 4);   // row within tile
        int c = pp & 15;               // 256-float chunk
        const float4 v =
            reinterpret_cast<const float4*>(x + (size_t)(row0 + r) * INF + c * 256)[lane];
        unsigned long long b0 = __ballot(v.x < 0.f);
        unsigned long long b1 = __ballot(v.y < 0.f);
        unsigned long long b2 = __ballot(v.z < 0.f);
        unsigned long long b3 = __ballot(v.w < 0.f);
        if (lane == 0) {
            // u64 word (c*4+j) lives at u32 index c*8+2j -> u64* offset c*4+j
            // from a base of &sX[r][c*8].
            uint64_t* dst = reinterpret_cast<uint64_t*>(&sX[r][c * 8]);
            dst[0] = b0; dst[1] = b1; dst[2] = b2; dst[3] = b3;
        }
    }
    __syncthreads();   // sX complete

    // ---- Phase 2: loop over 8 column tiles of 64 units. ----
    const int tx = t & 15;    // col group (cols tx+16j, strided -> 2-way LDS, free)
    const int ty = t >> 4;    // row group (rows ty+16i, broadcast, conflict-free)

    for (int tile = 0; tile < 8; ++tile) {
        if (tile) __syncthreads();     // previous compute done before restaging sW
        const uint4* gW = reinterpret_cast<const uint4*>(Wp + (size_t)tile * 64 * KW);
        #pragma unroll
        for (int i = 0; i < 8; ++i) {
            int idx4 = t + 256 * i;    // 2048 uint4 = 64 rows * 32
            int row  = idx4 >> 5;
            int col  = (idx4 & 31) * 4;
            *reinterpret_cast<uint4*>(&sW[row][col]) = gW[idx4];
        }
        __syncthreads();

        int acc[2][4] = {};
        #pragma unroll 4
        for (int k4 = 0; k4 < 32; ++k4) {
            uint4 xv[2], wv[4];
            #pragma unroll
            for (int i = 0; i < 2; ++i)
                xv[i] = *reinterpret_cast<const uint4*>(&sX[ty + 16 * i][k4 * 4]);
            #pragma unroll
            for (int j = 0; j < 4; ++j)
                wv[j] = *reinterpret_cast<const uint4*>(&sW[tx + 16 * j][k4 * 4]);
            #pragma unroll
            for (int i = 0; i < 2; ++i)
                #pragma unroll
                for (int j = 0; j < 4; ++j) {
                    acc[i][j] += __popc(xv[i].x ^ wv[j].x);
                    acc[i][j] += __popc(xv[i].y ^ wv[j].y);
                    acc[i][j] += __popc(xv[i].z ^ wv[j].z);
                    acc[i][j] += __popc(xv[i].w ^ wv[j].w);
                }
        }

        #pragma unroll
        for (int i = 0; i < 2; ++i) {
            int r = row0 + ty + 16 * i;
            #pragma unroll
            for (int j = 0; j < 4; ++j) {
                int u = tile * 64 + tx + 16 * j;
                C[(size_t)r * UNITS + u] = (float)(INF - 2 * acc[i][j]) + bias[u];
            }
        }
    }
}

extern "C" void kernel_launch(void* const* d_in, const int* in_sizes, int n_in,
                              void* d_out, int out_size, void* d_ws, size_t ws_size,
                              hipStream_t stream) {
    const float* x = (const float*)d_in[0];
    const float* W = (const float*)d_in[1];
    const float* b = (const float*)d_in[2];
    float* out = (float*)d_out;

    unsigned long long* Wp = (unsigned long long*)d_ws;   // 256 KB

    pack_w_kernel<<<32768 / 256, 256, 0, stream>>>(W, Wp);
    fused_kernel<<<BATCH / ROWS, 256, 0, stream>>>(
        x, (const uint32_t*)Wp, b, out);
}

// Round 4
// 126.560 us; speedup vs baseline: 1.2645x; 1.2645x over previous
//
#include <hip/hip_runtime.h>
#include <stdint.h>

// Binarized dense: C[r][u] = sum_k sign(x[r][k]) * sign(W[k][u]) + b[u]
//   sign(v) = +1 if v >= 0 else -1   -> bit(v) = (v < 0)
//   dot = F - 2 * popcount(xbits ^ wbits)
//
// Packed layout per row/col (F=4096 bits = 64 u64 words):
//   u64 word index w = c*4 + j,  c = 0..15 (256-float chunk), j = 0..3 (float4 comp)
//   bit i (0..63) of word (c,j) = bit(v[c*256 + i*4 + j])
// pack_x (ballot) and pack_w (bit loop) produce the identical layout; popcount
// is order-invariant so any consistent layout is correct. Both verified round 1.

#define BATCH  16384
#define INF    4096
#define UNITS  512
#define KW     128      // u32 words per row (4096/32)
#define KW64   64       // u64 words per row

// ---------------- pack x: [16384,4096] f32 -> [16384,64] u64 ----------------
__global__ __launch_bounds__(256) void pack_x_kernel(const float* __restrict__ x,
                                                     unsigned long long* __restrict__ Xp) {
    int wave = blockIdx.x * 4 + (threadIdx.x >> 6);
    int lane = threadIdx.x & 63;
    int r = wave >> 4;        // row 0..16383
    int c = wave & 15;        // 256-float chunk 0..15
    const float4 v = reinterpret_cast<const float4*>(x + (size_t)r * INF + c * 256)[lane];
    unsigned long long b0 = __ballot(v.x < 0.f);
    unsigned long long b1 = __ballot(v.y < 0.f);
    unsigned long long b2 = __ballot(v.z < 0.f);
    unsigned long long b3 = __ballot(v.w < 0.f);
    if (lane == 0) {
        unsigned long long* dst = Xp + (size_t)r * KW64 + c * 4;
        dst[0] = b0; dst[1] = b1; dst[2] = b2; dst[3] = b3;
    }
}

// ---------------- pack W: [4096,512] f32 -> [512,64] u64 --------------------
__global__ __launch_bounds__(256) void pack_w_kernel(const float* __restrict__ W,
                                                     unsigned long long* __restrict__ Wp) {
    int t  = blockIdx.x * 256 + threadIdx.x;   // 0..32767
    int u  = t & 511;                          // column
    int cj = t >> 9;                           // 0..63 = c*4 + j
    int j  = cj & 3;
    int c  = cj >> 2;
    const float* base = W + (size_t)(c * 256 + j) * UNITS + u;
    unsigned long long m = 0;
    #pragma unroll 16
    for (int i = 0; i < 64; ++i) {
        float v = base[(size_t)(4 * i) * UNITS];
        m |= (unsigned long long)(v < 0.f) << i;
    }
    Wp[(size_t)u * KW64 + cj] = m;
}

// -------- bit-GEMM v2: 128x128 tile, 8x8 per thread, BK=32 u32 words --------
// VALU/LDS balance per k4 per wave: 512 VALU insts (1024 cyc on one SIMD,
// /4 SIMDs = 256 CU-cyc) vs 16 ds_read_b128 (~192 CU-cyc) -> VALU-bound 1.33x.
// Pad 36: X reads (rows ty+16i, 4 distinct/wave) broadcast conflict-free;
// W reads (rows tx+16j) 2-way (free per m136). Staging writes 8-way conflicted
// but are 1/16 of LDS traffic.
__global__ __launch_bounds__(256, 2) void bgemm_kernel(const uint32_t* __restrict__ Xp,
                                                       const uint32_t* __restrict__ Wp,
                                                       const float* __restrict__ bias,
                                                       float* __restrict__ C) {
    __shared__ uint32_t sX[128][36];
    __shared__ uint32_t sW[128][36];
    const int t  = threadIdx.x;
    const int bx = blockIdx.x;   // col tile 0..3
    const int by = blockIdx.y;   // row tile 0..127
    const int tx = t & 15;
    const int ty = t >> 4;

    int acc[8][8] = {};

    for (int s = 0; s < 4; ++s) {
        if (s) __syncthreads();
        // stage 128 rows x 32 u32 words (= 8 uint4) of each operand
        #pragma unroll
        for (int i = 0; i < 4; ++i) {
            int idx = t + 256 * i;         // 0..1023
            int row = idx >> 3;
            int c4  = idx & 7;
            uint4 vx = reinterpret_cast<const uint4*>(
                Xp + ((size_t)(by * 128 + row)) * KW + s * 32)[c4];
            uint4 vw = reinterpret_cast<const uint4*>(
                Wp + ((size_t)(bx * 128 + row)) * KW + s * 32)[c4];
            *reinterpret_cast<uint4*>(&sX[row][c4 * 4]) = vx;
            *reinterpret_cast<uint4*>(&sW[row][c4 * 4]) = vw;
        }
        __syncthreads();

        #pragma unroll
        for (int k4 = 0; k4 < 8; ++k4) {
            uint4 xv[8], wv[8];
            #pragma unroll
            for (int i = 0; i < 8; ++i)
                xv[i] = *reinterpret_cast<const uint4*>(&sX[ty + 16 * i][k4 * 4]);
            #pragma unroll
            for (int j = 0; j < 8; ++j)
                wv[j] = *reinterpret_cast<const uint4*>(&sW[tx + 16 * j][k4 * 4]);
            #pragma unroll
            for (int i = 0; i < 8; ++i)
                #pragma unroll
                for (int j = 0; j < 8; ++j) {
                    acc[i][j] += __popc(xv[i].x ^ wv[j].x);
                    acc[i][j] += __popc(xv[i].y ^ wv[j].y);
                    acc[i][j] += __popc(xv[i].z ^ wv[j].z);
                    acc[i][j] += __popc(xv[i].w ^ wv[j].w);
                }
        }
    }

    #pragma unroll
    for (int i = 0; i < 8; ++i) {
        int r = by * 128 + ty + 16 * i;
        #pragma unroll
        for (int j = 0; j < 8; ++j) {
            int u = bx * 128 + tx + 16 * j;
            C[(size_t)r * UNITS + u] = (float)(INF - 2 * acc[i][j]) + bias[u];
        }
    }
}

extern "C" void kernel_launch(void* const* d_in, const int* in_sizes, int n_in,
                              void* d_out, int out_size, void* d_ws, size_t ws_size,
                              hipStream_t stream) {
    const float* x = (const float*)d_in[0];
    const float* W = (const float*)d_in[1];
    const float* b = (const float*)d_in[2];
    float* out = (float*)d_out;

    unsigned long long* Wp = (unsigned long long*)d_ws;                       // 256 KB
    unsigned long long* Xp = (unsigned long long*)((char*)d_ws + (1 << 20));  // 8 MB

    pack_w_kernel<<<32768 / 256, 256, 0, stream>>>(W, Wp);
    pack_x_kernel<<<(BATCH * 16) / 4, 256, 0, stream>>>(x, Xp);
    bgemm_kernel<<<dim3(UNITS / 128, BATCH / 128), 256, 0, stream>>>(
        (const uint32_t*)Xp, (const uint32_t*)Wp, b, out);
}